// Round 8
// baseline (205.542 us; speedup 1.0000x reference)
//
#include <hip/hip_runtime.h>

#define NPI    33600     // anchors per image: 160^2 + 80^2 + 40^2
#define KTOP   500
#define CAP    1024
#define KEY001 0xBC23D70Au   // monotonic key of 0.01f
#define NGRP   1024
#define NIMG   8
#define NBLK   34        // k_score blocks per image (25 + 7 + 2)
#define BCAPB  528       // candB storage (>= any non-degenerate boundary bin)

__device__ __forceinline__ float sigmoidf_(float x) {
  return 1.0f / (1.0f + expf(-x));
}
// monotonic float -> u32 key (order-preserving for all non-NaN floats)
__device__ __forceinline__ unsigned fkey(float f) {
  unsigned u = __float_as_uint(f);
  return (u & 0x80000000u) ? ~u : (u | 0x80000000u);
}

// ---------------- Kernel 1: streaming score pass (keys + per-block hist row) -----
// 4 anchors/thread float4 (16B/lane), level-major blocks (1024 anchors each).
// key = sigmoid(obj)*sigmoid(max raw cls) == obj*max(sigmoid(cls)) bitwise
// (sigmoid monotone) — proven absmax-0 rounds 1-7.
__global__ __launch_bounds__(256) void k_score(
    const float* __restrict__ p8, const float* __restrict__ p16,
    const float* __restrict__ p32,
    unsigned* __restrict__ keys, unsigned* __restrict__ histp)
{
  const int b  = blockIdx.y;
  const int xb = blockIdx.x;
  const float* lvl; int HW, j0, abase;
  if (xb < 25)      { lvl = p8;  HW = 25600; j0 = xb * 1024;        abase = 0; }
  else if (xb < 32) { lvl = p16; HW = 6400;  j0 = (xb - 25) * 1024; abase = 25600; }
  else              { lvl = p32; HW = 1600;  j0 = (xb - 32) * 1024; abase = 32000; }
  __shared__ unsigned lh[NGRP];
  for (int i = threadIdx.x; i < NGRP; i += 256) lh[i] = 0;
  __syncthreads();

  const int e = j0 + 4 * threadIdx.x;
  if (e < HW) {
    const float* base = lvl + (size_t)b * 85 * HW + e;
    float4 o4 = *(const float4*)(base + (size_t)4 * HW);
    float m0 = -INFINITY, m1 = -INFINITY, m2 = -INFINITY, m3 = -INFINITY;
    for (int c0 = 5; c0 < 85; c0 += 16) {      // 5 batches of 16 channels
      float4 r[16];
      #pragma unroll
      for (int u = 0; u < 16; ++u)
        r[u] = *(const float4*)(base + (size_t)(c0 + u) * HW);
      #pragma unroll
      for (int u = 0; u < 16; ++u) {
        m0 = fmaxf(m0, r[u].x); m1 = fmaxf(m1, r[u].y);
        m2 = fmaxf(m2, r[u].z); m3 = fmaxf(m3, r[u].w);
      }
    }
    float ov[4] = {o4.x, o4.y, o4.z, o4.w};
    float mv[4] = {m0, m1, m2, m3};
    unsigned k4[4];
    #pragma unroll
    for (int q = 0; q < 4; ++q) {
      float s = sigmoidf_(ov[q]) * sigmoidf_(mv[q]);
      k4[q] = fkey(s >= 0.01f ? s : -1.0f);
    }
    *(uint4*)(keys + (size_t)b * NPI + abase + e) = make_uint4(k4[0], k4[1], k4[2], k4[3]);
    #pragma unroll
    for (int q = 0; q < 4; ++q) atomicAdd(&lh[k4[q] >> 22], 1u);
  }
  __syncthreads();
  unsigned* gb = histp + ((size_t)b * NBLK + xb) * NGRP;
  for (int i = threadIdx.x; i < NGRP; i += 256) gb[i] = lh[i];   // plain stores
}

// ---------------- Kernel 2: per-image select + sort -> selected anchor list -----
// 512 threads (8 waves). Single-pass ballot compaction + fallback; wave-parallel
// threshold scans; P=512 sort when candidates fit.
__global__ __launch_bounds__(512) void k_select(
    const unsigned* __restrict__ histp, const unsigned* __restrict__ keys,
    unsigned* __restrict__ selanch, unsigned* __restrict__ invalg)
{
  const int b    = blockIdx.x;
  const int tid  = threadIdx.x;
  const int lane = tid & 63;
  const int wave = tid >> 6;

  __shared__ unsigned lh[NGRP];                         // 4 KB coarse hist
  __shared__ unsigned sh_sub[4096];                     // 16 KB refine hist
  __shared__ unsigned sh_c64[64];
  __shared__ unsigned sh_G, sh_chi10, sh_T;
  __shared__ int sh_ctrA, sh_ctrB;
  __shared__ __align__(16) unsigned long long sh_cand[CAP];     // 8 KB
  __shared__ __align__(16) unsigned long long sh_candB[BCAPB];  // 4.2 KB
  __shared__ unsigned sh_inval[16];
  __shared__ unsigned sh_wcB[8];

  // ---- A1: sum per-block hist rows -> lh (coalesced, no memset needed)
  {
    unsigned s0 = 0, s1 = 0;
    for (int r = 0; r < NBLK; ++r) {
      const unsigned* row = histp + ((size_t)b * NBLK + r) * NGRP;
      s0 += row[tid]; s1 += row[tid + 512];
    }
    lh[tid] = s0; lh[tid + 512] = s1;
  }
  for (int i = tid; i < 4096; i += 512) sh_sub[i] = 0;
  if (tid == 0) { sh_ctrA = 0; sh_ctrB = 0; }
  __syncthreads();
  if (tid < 64) {
    unsigned s = 0;
    #pragma unroll
    for (int k = 0; k < 16; ++k) s += lh[tid * 16 + ((k + tid) & 15)]; // swizzle: no bank conflict
    sh_c64[tid] = s;
  }
  __syncthreads();
  // ---- wave-parallel two-level scan -> G, chi10
  if (wave == 0) {
    unsigned v = sh_c64[lane];
    unsigned t = v;
    #pragma unroll
    for (int off = 1; off < 64; off <<= 1) {
      unsigned o = (unsigned)__shfl_down((int)t, off);
      if (lane + off < 64) t += o;
    }
    unsigned long long m = __ballot(t >= KTOP);
    int C = 63 - __builtin_clzll(m);           // highest lane with suffix >= KTOP
    unsigned cumAfter = (unsigned)__shfl((int)t, C) - (unsigned)__shfl((int)v, C);
    unsigned v2 = (lane < 16) ? lh[C * 16 + lane] : 0u;
    unsigned t2 = v2;
    #pragma unroll
    for (int off = 1; off < 16; off <<= 1) {
      unsigned o = (unsigned)__shfl_down((int)t2, off);
      if (lane + off < 16) t2 += o;
    }
    t2 += cumAfter;
    unsigned long long m2 = __ballot((lane < 16) && (t2 >= KTOP));
    int Gl = 63 - __builtin_clzll(m2);
    if (lane == 0) {
      sh_G = (unsigned)(C * 16 + Gl);
      sh_chi10 = (unsigned)__shfl((int)t2, Gl) - (unsigned)__shfl((int)v2, Gl);
    }
  }
  __syncthreads();
  const unsigned G = sh_G;
  const unsigned* kb = keys + (size_t)b * NPI;

  // ---- A2: 4096-bin sub-hist of bits [21:10] within group G
  for (int g = tid; g < NPI / 4; g += 512) {
    uint4 kv = ((const uint4*)kb)[g];
    unsigned kk[4] = {kv.x, kv.y, kv.z, kv.w};
    #pragma unroll
    for (int q = 0; q < 4; ++q)
      if ((kk[q] >> 22) == G) atomicAdd(&sh_sub[(kk[q] >> 10) & 4095u], 1u);
  }
  __syncthreads();
  if (tid < 64) {
    unsigned s = 0;
    for (int k = 0; k < 64; ++k) s += sh_sub[tid * 64 + ((k + tid) & 63)]; // swizzled
    sh_c64[tid] = s;
  }
  __syncthreads();
  if (wave == 0) {
    unsigned chi10 = sh_chi10;
    unsigned v = sh_c64[lane];
    unsigned t = v;
    #pragma unroll
    for (int off = 1; off < 64; off <<= 1) {
      unsigned o = (unsigned)__shfl_down((int)t, off);
      if (lane + off < 64) t += o;
    }
    t += chi10;
    unsigned long long m = __ballot(t >= KTOP);
    int C2 = 63 - __builtin_clzll(m);
    unsigned after = (unsigned)__shfl((int)t, C2) - (unsigned)__shfl((int)v, C2);
    unsigned v3 = sh_sub[C2 * 64 + lane];
    unsigned t3 = v3;
    #pragma unroll
    for (int off = 1; off < 64; off <<= 1) {
      unsigned o = (unsigned)__shfl_down((int)t3, off);
      if (lane + off < 64) t3 += o;
    }
    t3 += after;
    unsigned long long m3 = __ballot(t3 >= KTOP);
    int Gl = 63 - __builtin_clzll(m3);
    if (lane == 0) sh_T = (G << 12) | (unsigned)(C2 * 64 + Gl);   // 22-bit threshold
  }
  __syncthreads();
  const unsigned T = sh_T;

  // ---- Single-pass ballot-aggregated compaction (order-free; sort fixes order)
  for (int it = 0; it < 17; ++it) {           // 8400 groups / 512 threads
    int g = it * 512 + tid;
    bool act = (g < NPI / 4);
    uint4 kv = act ? ((const uint4*)kb)[g] : make_uint4(0, 0, 0, 0);
    unsigned kk[4] = {kv.x, kv.y, kv.z, kv.w};
    bool iA[4], iB[4];
    unsigned long long balA[4], balB[4];
    unsigned tA = 0, tB = 0;
    #pragma unroll
    for (int q = 0; q < 4; ++q) {
      unsigned bin = kk[q] >> 10;
      iA[q] = act && (bin > T);
      iB[q] = act && (bin == T);
      balA[q] = __ballot(iA[q]);
      balB[q] = __ballot(iB[q]);
      tA += (unsigned)__popcll(balA[q]);
      tB += (unsigned)__popcll(balB[q]);
    }
    int bA = 0, bB = 0;
    if (lane == 0) {
      if (tA) bA = atomicAdd(&sh_ctrA, (int)tA);
      if (tB) bB = atomicAdd(&sh_ctrB, (int)tB);
    }
    bA = __shfl(bA, 0); bB = __shfl(bB, 0);
    unsigned long long lt = (1ULL << lane) - 1ULL;
    unsigned offA = 0, offB = 0;
    #pragma unroll
    for (int q = 0; q < 4; ++q) {
      unsigned posA = (unsigned)bA + offA + (unsigned)__popcll(balA[q] & lt);
      unsigned posB = (unsigned)bB + offB + (unsigned)__popcll(balB[q] & lt);
      unsigned long long packed =
          ((unsigned long long)kk[q] << 32) |
          (unsigned long long)(0xFFFFFFFFu - (unsigned)(g * 4 + q));
      if (iA[q]) sh_cand[posA] = packed;
      if (iB[q] && posB < BCAPB) sh_candB[posB] = packed;
      offA += (unsigned)__popcll(balA[q]);
      offB += (unsigned)__popcll(balB[q]);
    }
  }
  __syncthreads();
  const int nA    = sh_ctrA;                  // < KTOP by construction of T
  const int nBtot = sh_ctrB;
  const int Bcap  = CAP - nA;
  const bool fast = (nBtot <= Bcap) && (nBtot <= BCAPB);
  int nBk;
  if (fast) {
    nBk = nBtot;
    for (int i2 = tid; i2 < nBtot; i2 += 512) sh_cand[nA + i2] = sh_candB[i2];
  } else {
    // Fallback (degenerate boundary bin): ordered two-pass for B, lowest indices kept
    nBk = (nBtot < Bcap) ? nBtot : Bcap;
    const int GPW2 = NPI / 4 / 8;             // 1050 groups per wave
    unsigned runB = 0;
    for (int it = 0; it < 17; ++it) {
      int gl = it * 64 + lane;
      bool act = (gl < GPW2);
      int g = wave * GPW2 + gl;
      uint4 kv = act ? ((const uint4*)kb)[g] : make_uint4(0, 0, 0, 0);
      unsigned kk[4] = {kv.x, kv.y, kv.z, kv.w};
      #pragma unroll
      for (int q = 0; q < 4; ++q)
        runB += (unsigned)__popcll(__ballot(act && ((kk[q] >> 10) == T)));
    }
    if (lane == 0) sh_wcB[wave] = runB;
    __syncthreads();
    unsigned pB = 0;
    for (int w2 = 0; w2 < wave; ++w2) pB += sh_wcB[w2];
    for (int it = 0; it < 17; ++it) {
      int gl = it * 64 + lane;
      bool act = (gl < GPW2);
      int g = wave * GPW2 + gl;
      uint4 kv = act ? ((const uint4*)kb)[g] : make_uint4(0, 0, 0, 0);
      unsigned kk[4] = {kv.x, kv.y, kv.z, kv.w};
      unsigned long long lt = (1ULL << lane) - 1ULL;
      #pragma unroll
      for (int q = 0; q < 4; ++q) {
        bool iB = act && ((kk[q] >> 10) == T);
        unsigned long long bal = __ballot(iB);
        unsigned pBl = pB + (unsigned)__popcll(bal & lt);
        if (iB && pBl < (unsigned)Bcap) {
          sh_cand[nA + pBl] =
              ((unsigned long long)kk[q] << 32) |
              (unsigned long long)(0xFFFFFFFFu - (unsigned)(g * 4 + q));
        }
        pB += (unsigned)__popcll(bal);
      }
    }
  }
  const int nTot = nA + nBk;                  // in [KTOP, CAP]
  const int P = (nTot <= 512) ? 512 : 1024;
  __syncthreads();
  for (int s = nTot + tid; s < P; s += 512) sh_cand[s] = 0ULL;
  __syncthreads();

  // ---- Bitonic sort P u64 descending ((score desc, index asc)); 1 exch/thread
  {
    const int half = P >> 1;
    for (unsigned kk2 = 2; kk2 <= (unsigned)P; kk2 <<= 1) {
      for (unsigned jj = kk2 >> 1; jj > 0; jj >>= 1) {
        if (tid < half) {
          unsigned i = (((unsigned)tid & ~(jj - 1)) << 1) | ((unsigned)tid & (jj - 1));
          unsigned p = i | jj;
          unsigned long long x = sh_cand[i], y = sh_cand[p];
          bool desc = ((i & kk2) == 0);
          if ((x < y) == desc) { sh_cand[i] = y; sh_cand[p] = x; }
        }
        __syncthreads();
      }
    }
  }

  // ---- Export selected anchors + invalid bitset
  bool validk = false;
  if (tid < KTOP) {
    unsigned long long v = sh_cand[tid];
    unsigned keyk = (unsigned)(v >> 32);
    int a = (int)(0xFFFFFFFFu - (unsigned)(v & 0xFFFFFFFFull));
    if (a < 0) a = 0;                 // zero-padded slot (invalid anyway)
    selanch[b * KTOP + tid] = (unsigned)a;
    validk = (keyk >= KEY001);
  }
  unsigned long long bv = __ballot((tid < KTOP) && !validk);
  if (lane == 0) {
    sh_inval[wave * 2]     = (unsigned)(bv & 0xFFFFFFFFull);
    sh_inval[wave * 2 + 1] = (unsigned)(bv >> 32);
  }
  __syncthreads();
  if (tid < 16) invalg[b * 16 + tid] = sh_inval[tid];
}

// ---------------- Kernel 3: decode selected anchors only (exact math) ----------
__global__ __launch_bounds__(256) void k_gather(
    const float* __restrict__ p8, const float* __restrict__ p16,
    const float* __restrict__ p32,
    const unsigned* __restrict__ selanch, float* __restrict__ seldet)
{
  const int b    = blockIdx.y;
  const int part = blockIdx.x;
  const int tid  = threadIdx.x;
  const int p    = tid & 15;            // lane within 16-lane group
  const int grp  = tid >> 4;            // 16 groups per 256 threads
  const int lane = tid & 63;
  const int g0   = lane & ~15;          // group base lane within wave

  for (int iter = 0; iter < 4; ++iter) {
    int s = part * 64 + iter * 16 + grp;
    if (s >= KTOP) continue;
    int a = (int)selanch[b * KTOP + s];
    const float* lvl; int j, W, HW, S;
    if (a < 25600)      { lvl = p8;  j = a;         W = 160; HW = 25600; S = 8;  }
    else if (a < 32000) { lvl = p16; j = a - 25600; W = 80;  HW = 6400;  S = 16; }
    else                { lvl = p32; j = a - 32000; W = 40;  HW = 1600;  S = 32; }
    const float* base = lvl + (size_t)b * 85 * HW + j;
    // lane p owns classes {p, p+16, ..., p+64} (ascending -> first occurrence)
    float cc = -1.0f; int lab = 0;
    #pragma unroll
    for (int u = 0; u < 5; ++u) {
      int c = p + 16 * u;
      float sv = sigmoidf_(base[(size_t)(5 + c) * HW]);
      if (sv > cc) { cc = sv; lab = c; }    // strict > : first occurrence
    }
    float tload = (p < 5) ? base[(size_t)p * HW] : 0.0f;
    // 16-lane reduce: max cc, ties -> smaller class index (= first occurrence)
    #pragma unroll
    for (int off = 1; off < 16; off <<= 1) {
      float occ = __shfl_xor(cc, off);
      int  olb = __shfl_xor(lab, off);
      if (occ > cc || (occ == cc && olb < lab)) { cc = occ; lab = olb; }
    }
    float t0 = __shfl(tload, g0 + 0);
    float t1 = __shfl(tload, g0 + 1);
    float t2 = __shfl(tload, g0 + 2);
    float t3 = __shfl(tload, g0 + 3);
    float t4 = __shfl(tload, g0 + 4);
    if (p == 0) {
      int gy = j / W, gx = j - gy * W;
      float fs = (float)S;
      float cx = (t0 + (float)gx) * fs;
      float cy = (t1 + (float)gy) * fs;
      float w  = expf(t2) * fs;
      float h  = expf(t3) * fs;
      float obj = sigmoidf_(t4);
      float* d = seldet + ((size_t)b * KTOP + s) * 7;
      d[0] = cx - 0.5f * w; d[1] = cy - 0.5f * h;
      d[2] = cx + 0.5f * w; d[3] = cy + 0.5f * h;
      d[4] = obj; d[5] = cc; d[6] = (float)lab;
    }
  }
}

// ---------------- Kernel 4: max_c + box offsets + IoU bitmask (16 x 8 blocks) ---
__global__ __launch_bounds__(256) void k_iou(
    const float* __restrict__ seldet, const unsigned* __restrict__ invalg,
    unsigned* __restrict__ gmask)
{
  const int w = blockIdx.x, b = blockIdx.y;
  const int tid = threadIdx.x;
  const int lane = tid & 63;
  const int wave = tid >> 6;
  __shared__ float sd[KTOP * 7];        // 14 KB det stage
  __shared__ float sx1[512], sy1[512], sx2[512], sy2[512], sa[512];
  __shared__ float sred[4];
  __shared__ float smaxc;
  for (int x = tid; x < KTOP * 7; x += 256)
    sd[x] = seldet[(size_t)b * (KTOP * 7) + x];
  __syncthreads();
  // max over valid boxes of max(x1,y1,x2,y2); invalid contribute 0 (ref where())
  float contrib = 0.0f;
  for (int i = tid; i < KTOP; i += 256) {
    bool valid = ((invalg[b * 16 + (i >> 5)] >> (i & 31)) & 1u) == 0u;
    float m4 = fmaxf(fmaxf(sd[i * 7 + 0], sd[i * 7 + 1]),
                     fmaxf(sd[i * 7 + 2], sd[i * 7 + 3]));
    contrib = fmaxf(contrib, valid ? m4 : 0.0f);
  }
  #pragma unroll
  for (int off = 32; off > 0; off >>= 1) contrib = fmaxf(contrib, __shfl_xor(contrib, off));
  if (lane == 0) sred[wave] = contrib;
  __syncthreads();
  if (tid == 0) smaxc = fmaxf(fmaxf(sred[0], sred[1]), fmaxf(sred[2], sred[3])) + 1.0f;
  __syncthreads();
  const float maxc = smaxc;
  for (int i = tid; i < 512; i += 256) {
    float x1, y1, x2, y2, ar;
    if (i < KTOP) {
      float offb = sd[i * 7 + 6] * maxc;    // label * max_c
      x1 = sd[i * 7 + 0] + offb; y1 = sd[i * 7 + 1] + offb;
      x2 = sd[i * 7 + 2] + offb; y2 = sd[i * 7 + 3] + offb;
      ar = fmaxf(x2 - x1, 0.0f) * fmaxf(y2 - y1, 0.0f);   // area of OFFSET box (ref)
    } else { x1 = y1 = x2 = y2 = ar = 0.0f; }
    sx1[i] = x1; sy1[i] = y1; sx2[i] = x2; sy2[i] = y2; sa[i] = ar;
  }
  __syncthreads();
  const int jbase = w * 32;
  for (int i = tid; i < KTOP; i += 256) {
    unsigned bits = 0u;
    if (jbase + 31 > i) {
      float ix1 = sx1[i], iy1 = sy1[i], ix2 = sx2[i], iy2 = sy2[i];
      float a1 = sa[i];
      #pragma unroll 4
      for (int jj = 0; jj < 32; ++jj) {
        int j = jbase + jj;
        if (j < KTOP && j > i) {
          float jx1 = sx1[j], jy1 = sy1[j];       // j uniform -> LDS broadcast
          float jx2 = sx2[j], jy2 = sy2[j];
          float a2  = sa[j];
          float iw = fminf(ix2, jx2) - fmaxf(ix1, jx1);
          float ih = fminf(iy2, jy2) - fmaxf(iy1, jy1);
          float inter = fmaxf(iw, 0.0f) * fmaxf(ih, 0.0f);
          // iou > 0.65  <=>  inter > 0.65*(a1+a2-inter+1e-9)
          if (inter > 0.65f * (a1 + a2 - inter + 1e-9f)) bits |= (1u << jj);
        }
      }
    }
    gmask[((size_t)b * 16 + w) * 512 + i] = bits;   // [b][w][i], coalesced
  }
}

// ---------------- Kernel 5: greedy scan + final write (8 blocks) ----------
__global__ __launch_bounds__(256) void k_nms(
    const unsigned* __restrict__ gmask, const unsigned* __restrict__ invalg,
    const float* __restrict__ seldet, float* __restrict__ out)
{
  const int b = blockIdx.x;
  const int tid = threadIdx.x;
  const int lane = tid & 63;
  __shared__ unsigned sm[KTOP * 17];     // [i][w], stride 17 -> conflict-free
  __shared__ unsigned sh_keep[16];
  for (int g = tid; g < KTOP * 16; g += 256) {
    int w = g / KTOP, i = g - w * KTOP;
    sm[i * 17 + w] = gmask[((size_t)b * 16 + w) * 512 + i];
  }
  __syncthreads();
  if (tid < 64) {
    unsigned sup   = (lane < 16) ? invalg[b * 16 + lane] : 0u;
    unsigned keepw = 0u;
    unsigned cur = (unsigned)__builtin_amdgcn_readlane((int)sup, 0);
    unsigned mA = (lane < 16) ? sm[0 * 17 + lane] : 0u;
    unsigned mB = (lane < 16) ? sm[1 * 17 + lane] : 0u;
    for (int i = 0; i < KTOP; i += 2) {
      bool ok = ((cur >> (i & 31)) & 1u) == 0u;
      if (ok) {
        sup |= mA;
        if (lane == (i >> 5)) keepw |= (1u << (i & 31));
      }
      cur = (unsigned)__builtin_amdgcn_readlane((int)sup, (i + 1) >> 5);
      mA = (lane < 16 && (i + 2) < KTOP) ? sm[(i + 2) * 17 + lane] : 0u;
      bool ok2 = ((cur >> ((i + 1) & 31)) & 1u) == 0u;
      if (ok2) {
        sup |= mB;
        if (lane == ((i + 1) >> 5)) keepw |= (1u << ((i + 1) & 31));
      }
      cur = (unsigned)__builtin_amdgcn_readlane((int)sup, (i + 2) >> 5);
      mB = (lane < 16 && (i + 3) < KTOP) ? sm[(i + 3) * 17 + lane] : 0u;
    }
    if (lane < 16) sh_keep[lane] = keepw;
  }
  __syncthreads();
  for (int x = tid; x < KTOP * 7; x += 256) {
    int k = x / 7;
    float keepf = ((sh_keep[k >> 5] >> (k & 31)) & 1u) ? 1.0f : 0.0f;
    out[(size_t)b * (KTOP * 7) + x] = seldet[(size_t)b * (KTOP * 7) + x] * keepf;
  }
}

extern "C" void kernel_launch(void* const* d_in, const int* in_sizes, int n_in,
                              void* d_out, int out_size, void* d_ws, size_t ws_size,
                              hipStream_t stream) {
  const float* p8  = (const float*)d_in[0];
  const float* p16 = (const float*)d_in[1];
  const float* p32 = (const float*)d_in[2];
  float* out = (float*)d_out;
  // workspace layout (~2.4 MB — L2-resident)
  unsigned* histp   = (unsigned*)d_ws;                          // [8][34][1024]
  unsigned* keys    = histp + (size_t)NIMG * NBLK * NGRP;       // [8][NPI]
  unsigned* selanch = keys + (size_t)NIMG * NPI;                // [8][500]
  unsigned* invalg  = selanch + (size_t)NIMG * KTOP;            // [8][16]
  unsigned* gmask   = invalg + NIMG * 16;                       // [8][16][512]
  float*    seldet  = (float*)(gmask + (size_t)NIMG * 16 * 512);// [8][500*7]

  k_score <<<dim3(NBLK, NIMG), 256, 0, stream>>>(p8, p16, p32, keys, histp);
  k_select<<<dim3(NIMG), 512, 0, stream>>>(histp, keys, selanch, invalg);
  k_gather<<<dim3(8, NIMG), 256, 0, stream>>>(p8, p16, p32, selanch, seldet);
  k_iou   <<<dim3(16, NIMG), 256, 0, stream>>>(seldet, invalg, gmask);
  k_nms   <<<dim3(NIMG), 256, 0, stream>>>(gmask, invalg, seldet, out);
}